// Round 4
// baseline (58.418 us; speedup 1.0000x reference)
//
#include <hip/hip_runtime.h>
#include <hip/hip_bf16.h>

// B=16, C=64, P=128, L=16, D=256, NPF=256, NRFF=128, FEAT=656
// ws layout (float slots):
#define WS_WK0   0        // 16     wk0 = Wk0^T q0
#define WS_A     16       // 256    A = Wq1^T Wk1
#define WS_E0    272      // 4096   E0 = Pp0 * Wv0  (256 x 16), f32 (for c0)
#define WS_BT    4368     // 20480 f32-slots = 40960 ushort: BTall[256][160] bf16
//   BTall[d][kk]: 0..15 Px; 16..31 E1; 32..95 Psin; 96..159 Pcos
// total 24848 floats ~ 100 KB

typedef float f32x4 __attribute__((ext_vector_type(4)));
typedef short s16x8 __attribute__((ext_vector_type(8)));
typedef short s16x4 __attribute__((ext_vector_type(4)));

static __device__ __forceinline__ short bf16b(float f) {
  __hip_bfloat16 h = __float2bfloat16(f);
  return __builtin_bit_cast(short, h);
}

__global__ __launch_bounds__(512)
void pre_kernel(const float* __restrict__ Wq, const float* __restrict__ Wk,
                const float* __restrict__ Wv, const float* __restrict__ pw,
                float* __restrict__ ws)
{
  // lds: [0..4095] mat1^T [l][d/f], [4096..8191] mat2^T, [8192..8447] q0
  __shared__ float lds[8448];
  const int t = threadIdx.x;
  const int blk = blockIdx.x;
  ushort* bt = (ushort*)(ws + WS_BT);

  if (blk == 0) {
    // stage Wq1^T and Wk1^T: thread t holds elems (d = t>>1, l = (t&1)*8 + 0..7)
    {
      const int d = t >> 1;
      const int lb = (t & 1) * 8;
      #pragma unroll
      for (int h = 0; h < 2; ++h) {
        const float4 vq = *(const float4*)(Wq + 4096 + t*8 + h*4);
        lds[(lb+h*4+0)*256 + d] = vq.x;
        lds[(lb+h*4+1)*256 + d] = vq.y;
        lds[(lb+h*4+2)*256 + d] = vq.z;
        lds[(lb+h*4+3)*256 + d] = vq.w;
        const float4 vk = *(const float4*)(Wk + 4096 + t*8 + h*4);
        lds[4096 + (lb+h*4+0)*256 + d] = vk.x;
        lds[4096 + (lb+h*4+1)*256 + d] = vk.y;
        lds[4096 + (lb+h*4+2)*256 + d] = vk.z;
        lds[4096 + (lb+h*4+3)*256 + d] = vk.w;
      }
    }
    if (t < 256) {
      float s = 0.f;
      #pragma unroll
      for (int q = 0; q < 4; ++q) {
        const float4 v = *(const float4*)(Wq + t*16 + q*4);
        s += v.x + v.y + v.z + v.w;           // q0[d] = sum_l Wq0[d,l]
      }
      lds[8192 + t] = s;
    }
    __syncthreads();
    if (t < 256) {
      const int l1 = t >> 4, l2 = t & 15;
      const float* r1 = lds + l1*256;
      const float* r2 = lds + 4096 + l2*256;
      float s = 0.f;
      #pragma unroll 8
      for (int dq = 0; dq < 64; ++dq) {
        const float4 a = *(const float4*)(r1 + dq*4);
        const float4 b = *(const float4*)(r2 + dq*4);
        s += a.x*b.x + a.y*b.y + a.z*b.z + a.w*b.w;    // A[l1,l2]
      }
      ws[WS_A + t] = s;
    }
    if (t < 16) {
      float s = 0.f;
      for (int d = 0; d < 256; ++d) s += lds[8192 + d] * Wk[d*16 + t];  // wk0[l]
      ws[WS_WK0 + t] = s;
    }
  } else if (blk <= 16) {
    const int deg = (blk <= 8) ? 0 : 1;
    // stage Wv[deg]^T: [l][f]
    {
      const int f = t >> 1;
      const int lb = (t & 1) * 8;
      #pragma unroll
      for (int h = 0; h < 2; ++h) {
        const float4 v = *(const float4*)(Wv + deg*4096 + t*8 + h*4);
        lds[(lb+h*4+0)*256 + f] = v.x;
        lds[(lb+h*4+1)*256 + f] = v.y;
        lds[(lb+h*4+2)*256 + f] = v.z;
        lds[(lb+h*4+3)*256 + f] = v.w;
      }
    }
    __syncthreads();
    const int d = ((blk-1) & 7)*32 + (t >> 4);
    const int l = t & 15;
    const float* pr = pw + d*656 + (deg ? 272 : 16);
    const float* wv = lds + l*256;
    float s = 0.f;
    #pragma unroll 8
    for (int fq = 0; fq < 64; ++fq) {
      const float4 a = *(const float4*)(pr + fq*4);
      const float4 b = *(const float4*)(wv + fq*4);
      s += a.x*b.x + a.y*b.y + a.z*b.z + a.w*b.w;
    }
    if (deg == 0) {
      ws[WS_E0 + d*16 + l] = s;                       // E0 f32 (exact, for c0)
      bt[d*160 + l] = (ushort)bf16b(pw[d*656 + l]);   // Px
    } else {
      bt[d*160 + 16 + l] = (ushort)bf16b(s);          // E1
    }
  } else {
    // blk 17: sin/cos projection weights, coalesced along j
    #pragma unroll 4
    for (int k = 0; k < 64; ++k) {
      const int d = k*4 + (t >> 7);
      const int j = t & 127;
      const float v = (j < 64) ? pw[d*656 + 528 + j] : pw[d*656 + 592 + (j-64)];
      bt[d*160 + 32 + j] = (ushort)bf16b(v);
    }
  }
}

__global__ __launch_bounds__(256, 2)
void main_kernel(const float* __restrict__ x, const float* __restrict__ fw,
                 const float* __restrict__ fb, const float* __restrict__ pw,
                 const float* __restrict__ pb, const float* __restrict__ ws,
                 float* __restrict__ out)
{
  __shared__ float XsT[16*68];     // f32 x^T [l][c] (LD=68 keeps 16B align + low conflicts)
  __shared__ float fws[16*64];
  __shared__ float fbs[64];
  __shared__ float Gs[256];        // G = X^T X
  __shared__ float N1s[256];       // N1 = A*G
  __shared__ float tls[16];        // t = G*wk0
  __shared__ float c0s[256];       // pb[d] + sum_l t[l]*E0[d,l]
  __shared__ short Abf[20*64*8];   // bf16 acts [kt][c][8]: kt0-1=x, kt2-3=M=X*N1, kt4-11=sin, kt12-19=cos

  const int t = threadIdx.x;
  const int b = blockIdx.x >> 7;
  const int p = blockIdx.x & 127;

  // ---- phase 1: stage X (f32 + bf16 kt0-1), fw, fb ----
  {
    const int c = t >> 2, l0 = (t & 3) * 4;
    const float4 v = *(const float4*)(x + (((b*64 + c)*128 + p) << 4) + l0);
    XsT[(l0+0)*68 + c] = v.x;
    XsT[(l0+1)*68 + c] = v.y;
    XsT[(l0+2)*68 + c] = v.z;
    XsT[(l0+3)*68 + c] = v.w;
    s16x4 xb;
    xb[0] = bf16b(v.x); xb[1] = bf16b(v.y); xb[2] = bf16b(v.z); xb[3] = bf16b(v.w);
    *(s16x4*)&Abf[(((l0>>3)*64 + c) << 3) + (l0 & 4)] = xb;
  }
  *(float4*)(fws + t*4) = *(const float4*)(fw + t*4);
  if (t < 16) *(float4*)(fbs + t*4) = *(const float4*)(fb + t*4);
  __syncthreads();

  // ---- phase 2: G (float4), wx (hoisted xv + float4 fws) + sincos -> Abf ----
  {
    const int l1 = t >> 4, l2 = t & 15;
    const float* r1 = XsT + l1*68;
    const float* r2 = XsT + l2*68;
    float g = 0.f;
    #pragma unroll
    for (int cq = 0; cq < 16; ++cq) {
      const float4 a = *(const float4*)(r1 + cq*4);
      const float4 bb = *(const float4*)(r2 + cq*4);
      g += a.x*bb.x + a.y*bb.y + a.z*bb.z + a.w*bb.w;
    }
    Gs[t] = g;
  }
  {
    const int c = t & 63, jb = t >> 6;
    float wx[16];
    {
      const float4 b0 = *(const float4*)(fbs + jb*16);
      const float4 b1 = *(const float4*)(fbs + jb*16 + 4);
      const float4 b2 = *(const float4*)(fbs + jb*16 + 8);
      const float4 b3 = *(const float4*)(fbs + jb*16 + 12);
      wx[0]=b0.x; wx[1]=b0.y; wx[2]=b0.z; wx[3]=b0.w;
      wx[4]=b1.x; wx[5]=b1.y; wx[6]=b1.z; wx[7]=b1.w;
      wx[8]=b2.x; wx[9]=b2.y; wx[10]=b2.z; wx[11]=b2.w;
      wx[12]=b3.x; wx[13]=b3.y; wx[14]=b3.z; wx[15]=b3.w;
    }
    #pragma unroll
    for (int l = 0; l < 16; ++l) {
      const float xv = XsT[l*68 + c];
      const float4 f0 = *(const float4*)(fws + l*64 + jb*16);
      const float4 f1 = *(const float4*)(fws + l*64 + jb*16 + 4);
      const float4 f2 = *(const float4*)(fws + l*64 + jb*16 + 8);
      const float4 f3 = *(const float4*)(fws + l*64 + jb*16 + 12);
      wx[0] += xv*f0.x; wx[1] += xv*f0.y; wx[2] += xv*f0.z; wx[3] += xv*f0.w;
      wx[4] += xv*f1.x; wx[5] += xv*f1.y; wx[6] += xv*f1.z; wx[7] += xv*f1.w;
      wx[8] += xv*f2.x; wx[9] += xv*f2.y; wx[10] += xv*f2.z; wx[11] += xv*f2.w;
      wx[12] += xv*f3.x; wx[13] += xv*f3.y; wx[14] += xv*f3.z; wx[15] += xv*f3.w;
    }
    s16x8 ps0, ps1, pc0, pc1;
    #pragma unroll
    for (int k = 0; k < 8; ++k) {
      float sv, cv;
      __sincosf(wx[k], &sv, &cv);
      ps0[k] = bf16b(sv); pc0[k] = bf16b(cv);
    }
    #pragma unroll
    for (int k = 0; k < 8; ++k) {
      float sv, cv;
      __sincosf(wx[8+k], &sv, &cv);
      ps1[k] = bf16b(sv); pc1[k] = bf16b(cv);
    }
    *(s16x8*)&Abf[(((4 + 2*jb)*64 + c) << 3)] = ps0;
    *(s16x8*)&Abf[(((5 + 2*jb)*64 + c) << 3)] = ps1;
    *(s16x8*)&Abf[(((12 + 2*jb)*64 + c) << 3)] = pc0;
    *(s16x8*)&Abf[(((13 + 2*jb)*64 + c) << 3)] = pc1;
  }
  __syncthreads();

  // ---- phase 3: N1 = A*G ; tls = G*wk0 ----
  {
    const int l1 = t >> 4, l2 = t & 15;
    float a[16];
    #pragma unroll
    for (int q = 0; q < 4; ++q)
      *(float4*)(a + q*4) = *(const float4*)(ws + WS_A + l1*16 + q*4);
    float s = 0.f;
    #pragma unroll
    for (int k = 0; k < 16; ++k) s += a[k] * Gs[k*16 + l2];
    N1s[t] = s;
  }
  if (t < 16) {
    float wk[16], gr[16];
    #pragma unroll
    for (int q = 0; q < 4; ++q) {
      *(float4*)(wk + q*4) = *(const float4*)(ws + WS_WK0 + q*4);
      *(float4*)(gr + q*4) = *(const float4*)(Gs + t*16 + q*4);
    }
    float s = 0.f;
    #pragma unroll
    for (int k = 0; k < 16; ++k) s += gr[k] * wk[k];
    tls[t] = s;
  }
  __syncthreads();

  // ---- phase 4: M = X*N1 -> Abf kt2-3 ; c0[d] ----
  {
    const int c = t >> 2, lp0 = (t & 3) * 4;
    float m0 = 0.f, m1 = 0.f, m2 = 0.f, m3 = 0.f;
    #pragma unroll
    for (int l = 0; l < 16; ++l) {
      const float xv = XsT[l*68 + c];
      const float4 n = *(const float4*)(N1s + l*16 + lp0);
      m0 += xv * n.x; m1 += xv * n.y; m2 += xv * n.z; m3 += xv * n.w;
    }
    s16x4 mb;
    mb[0] = bf16b(m0); mb[1] = bf16b(m1); mb[2] = bf16b(m2); mb[3] = bf16b(m3);
    *(s16x4*)&Abf[(((2 + (lp0>>3))*64 + c) << 3) + (lp0 & 4)] = mb;
  }
  {
    const int d = t;
    float e[16], tl[16];
    #pragma unroll
    for (int q = 0; q < 4; ++q) {
      *(float4*)(e + q*4) = *(const float4*)(ws + WS_E0 + d*16 + q*4);
      *(float4*)(tl + q*4) = *(const float4*)(tls + q*4);
    }
    float s = pb[d];
    #pragma unroll
    for (int l = 0; l < 16; ++l) s += tl[l] * e[l];
    c0s[d] = s;
  }
  __syncthreads();

  // ---- phase 5: MFMA, A=weights (rows=d), B=activations (cols=c) ----
  const int lane = t & 63, w = t >> 6;
  const int n0 = w << 6;                 // wave's d-offset
  const int lr = lane & 15, lq = lane >> 4;
  f32x4 acc[4][4] = {};                  // [mi: d-tile][nt: c-tile]
  const ushort* BTW = (const ushort*)(ws + WS_BT);
  #pragma unroll
  for (int ks = 0; ks < 5; ++ks) {
    s16x8 af[4], bf_[4];
    #pragma unroll
    for (int mi = 0; mi < 4; ++mi)
      af[mi] = *(const s16x8*)&BTW[(n0 + mi*16 + lr)*160 + ks*32 + lq*8];
    #pragma unroll
    for (int nt = 0; nt < 4; ++nt)
      bf_[nt] = *(const s16x8*)&Abf[(((ks*4 + lq)*64) + nt*16 + lr) << 3];
    #pragma unroll
    for (int mi = 0; mi < 4; ++mi)
      #pragma unroll
      for (int nt = 0; nt < 4; ++nt)
        acc[mi][nt] = __builtin_amdgcn_mfma_f32_16x16x32_bf16(af[mi], bf_[nt], acc[mi][nt], 0, 0, 0);
  }

  // ---- epilogue: D row = d (lq*4+r consecutive) -> float4 stores ----
  float4 cv[4];
  #pragma unroll
  for (int mi = 0; mi < 4; ++mi)
    cv[mi] = *(const float4*)(c0s + n0 + mi*16 + (lq << 2));
  #pragma unroll
  for (int nt = 0; nt < 4; ++nt) {
    const int c = nt*16 + lr;
    float* rp = out + (((b*64 + c)*128 + p) << 8) + n0 + (lq << 2);
    #pragma unroll
    for (int mi = 0; mi < 4; ++mi) {
      float4 o;
      o.x = acc[mi][nt][0] + cv[mi].x;
      o.y = acc[mi][nt][1] + cv[mi].y;
      o.z = acc[mi][nt][2] + cv[mi].z;
      o.w = acc[mi][nt][3] + cv[mi].w;
      *(float4*)(rp + mi*16) = o;
    }
  }
}

extern "C" void kernel_launch(void* const* d_in, const int* in_sizes, int n_in,
                              void* d_out, int out_size, void* d_ws, size_t ws_size,
                              hipStream_t stream) {
  const float* x  = (const float*)d_in[0];
  const float* Wq = (const float*)d_in[1];
  const float* Wk = (const float*)d_in[2];
  const float* Wv = (const float*)d_in[3];
  const float* fw = (const float*)d_in[4];
  const float* fb = (const float*)d_in[5];
  const float* pw = (const float*)d_in[6];
  const float* pb = (const float*)d_in[7];
  float* out = (float*)d_out;
  float* ws  = (float*)d_ws;   // needs 24848 floats ~ 100 KB

  pre_kernel<<<18, 512, 0, stream>>>(Wq, Wk, Wv, pw, ws);
  main_kernel<<<16*128, 256, 0, stream>>>(x, fw, fb, pw, pb, ws, out);
}